// Round 1
// baseline (111.685 us; speedup 1.0000x reference)
//
#include <hip/hip_runtime.h>

// MXIntSoftmax — bit-exact integer port, round 7: 1 row/block, 8 elems/thread.
//
// Semantics (verified absmax=0 in R1/R3/R4/R5 and prior session):
//   yq    = clip(floor(clip(rne(x*2^(7-e)),-128,127) * 46 * 2^(e-7+5)), -256, 255),
//           e = clip(ceil(log2|x|),-8,7)  — exponent-field bit math + f32 (exact)
//   e8    = (yq>>5)+8 in [0,15] ; me = rint(exp2((yq&31)/32+6)) in [64,125]
//   scan  -> single floor: partial += ((me<<4) >> (E8-e8)) << E8, E8 = prefix max of e8
//           (prefix order == memory order along D: round 0 of all 4 waves, then round 1)
//   msum  = total >> Estar8 in [1024,2^22) ; magic = floor(2^38/msum)+1 (f64, exact)
//   out   = finalLUT[yq+256] — fuses mout=floor(me*256/msum) and mxint quant.
//
// R7 change vs R6: 2 rows/block/16-elem -> 1 row/block/8-elem. Halves the
// per-block serial chain (scan round-trips, gathers, barrier segments), drops
// live VGPRs (yq[8]+v[2]) to fit launch_bounds(256,8) = 32 waves/CU.

#define D_DIM 2048
#define TPB   256

// byte-wise max of two u32 whose bytes are <= 15
__device__ __forceinline__ unsigned bmax4(unsigned x, unsigned y) {
    const unsigned d     = (x | 0x80808080u) - y;
    const unsigned flags = d & 0x80808080u;
    const unsigned mask  = (flags - (flags >> 7)) | flags;
    return (x & mask) | (y & ~mask);
}

__global__ __launch_bounds__(TPB, 8) void mxint_softmax_kernel(const float* __restrict__ x,
                                                               float* __restrict__ out) {
    const int t    = threadIdx.x;
    const int lane = t & 63;
    const int wid  = t >> 6;           // 4 waves, all on the same row
    const int row  = blockIdx.x;

    __shared__ unsigned short     s_pk[512];       // me<<4 keyed by yq+256 (static)
    __shared__ float              s_fin[512];      // fused output LUT (this row)
    __shared__ unsigned           s_rmax[4];       // per-wave packed round maxima (2 bytes)
    __shared__ unsigned long long s_part[4];       // per-wave partial sums

    // ---- issue global loads first: 2 rounds x float4, coalesced ----
    const size_t base = (size_t)row * D_DIM + t * 4;
    float4 v[2];
#pragma unroll
    for (int i = 0; i < 2; ++i)
        v[i] = *(const float4*)(x + base + i * 1024);

    // ---- static pk LUT: 2 entries/thread, overlaps load latency ----
#pragma unroll
    for (int q = 0; q < 2; ++q) {
        const int idx = t + 256 * q;
        const float a = fmaf((float)(idx & 31), 0.03125f, 6.0f);
        const int  me = (int)rintf(__builtin_amdgcn_exp2f(a));   // exact TAB match
        s_pk[idx] = (unsigned short)(me << 4);
    }

    // ---- front end: yq per element; per-round maxima packed as bytes ----
    int yq[8];
    unsigned pe = 0;
#pragma unroll
    for (int i = 0; i < 2; ++i) {
        const float xs4[4] = {v[i].x, v[i].y, v[i].z, v[i].w};
        int rmaxr = -256;
#pragma unroll
        for (int k = 0; k < 4; ++k) {
            const unsigned b  = __float_as_uint(xs4[k]) & 0x7fffffffu;
            const unsigned tb = b + 0x7fffffu;
            const unsigned tc = min(max(tb, 0x3B800000u), 0x43000000u);  // clamp exp field
            const unsigned es = tc & 0xFF800000u;                        // ebc<<23
            const float    su  = __uint_as_float(0x82800000u - es);      // 2^(134-ebc)
            const float    fac = __uint_as_float(es + 0xFF380000u);      // 46*2^(ebc-134)
            const float    mi  = __builtin_amdgcn_fmed3f(rintf(xs4[k] * su), -128.0f, 127.0f);
            int y = (int)floorf(mi * fac);                               // exact product
            y = min(255, max(-256, y));
            yq[4 * i + k] = y;
            rmaxr = max(rmaxr, y);
        }
        pe |= (unsigned)((rmaxr >> 5) + 8) << (8 * i);     // biased e8 round-max byte
    }

    // ---- one SWAR wave scan (2 round-bytes at once; upper bytes stay 0) ----
    unsigned s = pe;
#pragma unroll
    for (int d = 1; d < 64; d <<= 1) {
        const unsigned o = __shfl_up(s, d, 64);
        if (lane >= d) s = bmax4(s, o);
    }
    unsigned ex = __shfl_up(s, 1, 64);
    if (lane == 0) ex = 0;
    const unsigned bc = __shfl(s, 63, 64);                 // per-round wave totals
    s_rmax[wid] = bc;
    __syncthreads();                                       // B1: pk LUT + wave totals ready

    // ---- cross-wave carries (memory order: round 0 all waves, then round 1) ----
    const unsigned w0 = s_rmax[0], w1 = s_rmax[1], w2 = s_rmax[2], w3 = s_rmax[3];
    int c0 = 0, c1p = 0;                                   // prefix over waves < wid
    if (wid > 0) { c0 = (int)(w0 & 255u);          c1p = (int)((w0 >> 8) & 255u); }
    if (wid > 1) { c0 = max(c0, (int)(w1 & 255u)); c1p = max(c1p, (int)((w1 >> 8) & 255u)); }
    if (wid > 2) { c0 = max(c0, (int)(w2 & 255u)); c1p = max(c1p, (int)((w2 >> 8) & 255u)); }
    const unsigned mall = bmax4(bmax4(w0, w1), bmax4(w2, w3));
    const int A0     = (int)(mall & 255u);                 // block max of round 0
    const int c1     = max(A0, c1p);                       // carry into round 1
    const int Estar8 = max(A0, (int)((mall >> 8) & 255u)); // global row max (biased)

    // ---- weighted sum (collapsed scan), u32 partial (8 terms < 2^29) ----
    unsigned partial = 0;
    const int cs[2] = {c0, c1};
#pragma unroll
    for (int i = 0; i < 2; ++i) {
        int a = max(cs[i], (int)((ex >> (8 * i)) & 255u));
#pragma unroll
        for (int k = 0; k < 4; ++k) {
            const int y  = yq[4 * i + k];
            const int h  = (y >> 5) + 8;                   // e8 biased [0,15]
            a = max(a, h);                                 // inclusive prefix max
            const unsigned me4 = s_pk[y + 256];            // me<<4
            partial += (me4 >> (a - h)) << a;              // floor term << (E+8)
        }
    }

    // ---- butterfly reduce within wave (1 u32 step, then u64) ----
    const unsigned ps = partial + __shfl_xor(partial, 1, 64);   // pair < 2^30, safe
    unsigned long long p64 = ps;
#pragma unroll
    for (int d = 2; d < 64; d <<= 1) p64 += __shfl_xor(p64, d, 64);
    s_part[wid] = p64;          // benign same-value write by all lanes
    __syncthreads();            // B2: partials ready

    const unsigned long long tot = s_part[0] + s_part[1] + s_part[2] + s_part[3];
    const unsigned msum   = (unsigned)(tot >> Estar8);          // [1024, 2^22)
    const unsigned magic  = (unsigned)(274877906944.0 / (double)msum) + 1u;  // floor(2^38/m)+1

    // ---- fused final LUT: 2 entries per thread ----
#pragma unroll
    for (int q = 0; q < 2; ++q) {
        const int      idx  = t + 256 * q;                 // 0..511  (yq = idx-256)
        const unsigned me4  = s_pk[idx];
        const unsigned mout = __umulhi(me4 << 4, magic) >> 6;   // floor(me*256/msum), [0,31]
        const int      e8   = idx >> 5;                        // == (yq>>5)+8
        const int      eoutn = Estar8 - e8;                    // [0,15] for reachable entries
        const int      bl   = 32 - __clz((int)(mout | 1u));
        const int      pw2  = ((mout & (mout - 1u)) == 0u) ? 1 : 0;
        const int      clog = bl - pw2;
        const int      sq   = min(7 - clog, 11 - eoutn);
        const int      rs   = 8 - sq;                          // [1,12]
        const unsigned u    = mout << 8;
        const unsigned bse  = u >> rs;
        const unsigned frac = u & ((1u << rs) - 1u);
        const unsigned hlf  = 1u << (rs - 1);
        unsigned m2 = bse + (((frac > hlf) || (frac == hlf && (bse & 1u))) ? 1u : 0u);
        m2 = min(m2, 127u);
        const int ef = max(clog - eoutn - 4, -8);
        s_fin[idx] = (float)m2 * __uint_as_float((unsigned)(ef + 120) << 23);
    }
    __syncthreads();            // B3: final LUT ready

    // ---- epilogue: one LDS read per element, coalesced float4 stores ----
    float* orow = out + base;
#pragma unroll
    for (int i = 0; i < 2; ++i) {
        float r4[4];
#pragma unroll
        for (int k = 0; k < 4; ++k)
            r4[k] = s_fin[yq[4 * i + k] + 256];
        const float4 o4 = {r4[0], r4[1], r4[2], r4[3]};
        *(float4*)(orow + i * 1024) = o4;
    }
}

extern "C" void kernel_launch(void* const* d_in, const int* in_sizes, int n_in,
                              void* d_out, int out_size, void* d_ws, size_t ws_size,
                              hipStream_t stream) {
    const float* x = (const float*)d_in[0];
    float*       o = (float*)d_out;
    const int rows = in_sizes[0] / D_DIM;      // 8192
    mxint_softmax_kernel<<<rows, TPB, 0, stream>>>(x, o);
}